// Round 6
// baseline (1198.715 us; speedup 1.0000x reference)
//
#include <hip/hip_runtime.h>
#include <hip/hip_bf16.h>

typedef __bf16 bf16x8 __attribute__((ext_vector_type(8)));
typedef float f32x4 __attribute__((ext_vector_type(4)));

#define NB 512
#define NT 256
#define ND 64
#define NH 128
#define PART_IDX 256      /* WS float slots 256..287: per-block loss partials */
#define FLAG_IDX 320      /* WS float slot: 1.0 = inputs are f32, 0.0 = bf16 */
#define PACK_OFF 8192     /* byte offset of packed weights in d_ws */
#define NFRAG 8192        /* fragments per matrix: 4g * 4kk * 8w * 64l */

__device__ __forceinline__ float bf2f(__hip_bfloat16 v){ return __bfloat162float(v); }
__device__ __forceinline__ __hip_bfloat16 f2bf(float v){ return __float2bfloat16(v); }

__device__ __forceinline__ float ldF(const float* p){ return *p; }
__device__ __forceinline__ float ldF(const __hip_bfloat16* p){ return __bfloat162float(*p); }
__device__ __forceinline__ void  stF(float* p, float v){ *p = v; }
__device__ __forceinline__ void  stF(__hip_bfloat16* p, float v){ *p = __float2bfloat16(v); }

// paired load -> 2 floats
__device__ __forceinline__ void ld2(const float* p, float& a, float& b){
    float2 v = *reinterpret_cast<const float2*>(p); a = v.x; b = v.y;
}
__device__ __forceinline__ void ld2(const __hip_bfloat16* p, float& a, float& b){
    unsigned u = *reinterpret_cast<const unsigned*>(p);
    unsigned short s0 = (unsigned short)(u & 0xffffu), s1 = (unsigned short)(u >> 16);
    a = __bfloat162float(*reinterpret_cast<__hip_bfloat16*>(&s0));
    b = __bfloat162float(*reinterpret_cast<__hip_bfloat16*>(&s1));
}

// dtype-generic 8-element MFMA fragment load (16B for bf16, 32B for f32 + cvt)
__device__ __forceinline__ bf16x8 ldfrag(const __hip_bfloat16* p){
    return *reinterpret_cast<const bf16x8*>(p);
}
__device__ __forceinline__ bf16x8 ldfrag(const float* p){
    f32x4 a = *reinterpret_cast<const f32x4*>(p);
    f32x4 b = *reinterpret_cast<const f32x4*>(p + 4);
    bf16x8 r;
    #pragma unroll
    for (int i = 0; i < 4; ++i){
        __hip_bfloat16 ha = __float2bfloat16(a[i]);
        __hip_bfloat16 hb = __float2bfloat16(b[i]);
        r[i]   = *reinterpret_cast<__bf16*>(&ha);
        r[4+i] = *reinterpret_cast<__bf16*>(&hb);
    }
    return r;
}
__device__ __forceinline__ bf16x8 ldbf8(const __hip_bfloat16* p){
    return *reinterpret_cast<const bf16x8*>(p);
}

template<typename T> __device__ __forceinline__ float wantFlag(){ return sizeof(T)==4 ? 1.f : 0.f; }

__device__ __forceinline__ f32x4 mfma16(bf16x8 a, bf16x8 b, f32x4 c){
    return __builtin_amdgcn_mfma_f32_16x16x32_bf16(a, b, c, 0, 0, 0);
}
__device__ __forceinline__ float fsig(float x){ return 1.f/(1.f+__expf(-x)); }
__device__ __forceinline__ float ftanh(float x){ return 1.f - 2.f/(__expf(2.f*x)+1.f); }

// --------------------- kernel 0: input dtype detection ---------------------
__global__ void detect_kernel(const void* __restrict__ x, float* __restrict__ WS){
    if (threadIdx.x == 0 && blockIdx.x == 0){
        const unsigned short* u = (const unsigned short*)x;
        int weird = 0;
        for (int i = 0; i < 256; ++i){
            unsigned e = (u[i] >> 7) & 0xFF;
            if (e == 0xFF || e >= 0x8A || (e != 0 && e <= 0x5A)) ++weird;
        }
        WS[FLAG_IDX] = (weird >= 16) ? 1.f : 0.f;
    }
}

// --------------------- kernel 0b: pack LSTM weights to bf16 fragments ---------------------
// Fragment index f = ((g*4+kk)*8+w)*64 + l ; lane l = lg*16+lr owns
// Wih/Whh[(g*128 + 16w + lr)*128 + kk*32 + lg*8 .. +8).
template<typename T>
__global__ __launch_bounds__(256) void pack_kernel(const T* __restrict__ Wih,
                                                   const T* __restrict__ Whh,
                                                   float* __restrict__ WS){
    if (WS[FLAG_IDX] != wantFlag<T>()) return;
    int f = blockIdx.x * 256 + threadIdx.x;       // 0..8191
    int l  = f & 63;
    int w  = (f >> 6) & 7;
    int kk = (f >> 9) & 3;
    int g  = (f >> 11) & 3;
    int lr = l & 15, lg = l >> 4;
    size_t row = (size_t)(g*NH + 16*w + lr);
    int col = kk*32 + lg*8;
    bf16x8* PW = (bf16x8*)((char*)WS + PACK_OFF);
    PW[f]         = ldfrag(Wih + row*128 + col);
    PW[NFRAG + f] = ldfrag(Whh + row*128 + col);
}

// --------------------- kernel 1: per-step inverse mask sum ---------------------
template<typename T>
__global__ __launch_bounds__(256) void msum_kernel(const T* __restrict__ M,
                                                   float* __restrict__ WS){
    if (WS[FLAG_IDX] != wantFlag<T>()) return;
    int t = blockIdx.x;
    int tid = threadIdx.x;
    int col = tid & 63;
    int bg  = tid >> 6;
    float s = 0.f;
    for (int b = bg; b < NB; b += 4)
        s += ldF(&M[((size_t)b*NT + t)*ND + col]);
    #pragma unroll
    for (int off = 32; off > 0; off >>= 1) s += __shfl_down(s, off);
    __shared__ float r4[4];
    if ((tid & 63) == 0) r4[bg] = s;
    __syncthreads();
    if (tid == 0) WS[t] = 1.f / (r4[0] + r4[1] + r4[2] + r4[3] + 1e-5f);
}

// --------------------- main: 32 blocks x 512 threads, 16 batch rows each ---------------------
template<typename T>
__global__ __launch_bounds__(512, 2) void brits_main(
    const T* __restrict__ X,  const T* __restrict__ M,
    const T* __restrict__ DL,
    const T* __restrict__ Wdh, const T* __restrict__ bdh,
    const T* __restrict__ Wdx, const T* __restrict__ bdx,
    const T* __restrict__ Whr, const T* __restrict__ bhr,
    const T* __restrict__ Wfr, const T* __restrict__ bfr,
    const T* __restrict__ Wwc, const T* __restrict__ bwc,
    const T* __restrict__ Wih, const T* __restrict__ Whh,
    const T* __restrict__ bih, const T* __restrict__ bhh,
    T* __restrict__ OUT, float* __restrict__ WS)
{
    if (WS[FLAG_IDX] != wantFlag<T>()) return;

    // static LDS (~28 KB), bf16 MFMA-A regions padded to de-conflict ds_read_b128
    __shared__ __align__(16) __hip_bfloat16 sAg[16][264];   // [ c_c(0:64) | m(64:128) | h_bf(128:256) ]
    __shared__ __align__(16) __hip_bfloat16 sAal[16][136];  // [ gamma_x(0:64) | m(64:128) ]
    __shared__ __align__(16) __hip_bfloat16 sXc[16][72];    // x_c
    __shared__ float sX [16][68];                           // x(t) as f32
    __shared__ float sXh[16][68];
    __shared__ float sZh[16][68];
    __shared__ float sAl[16][68];
    __shared__ float sRed[8];
    // dynamic LDS: parked Whh packed fragments (131072 B = 8192 x 16B)
    extern __shared__ __align__(16) char dynLDS[];
    bf16x8* sWhh = (bf16x8*)dynLDS;

    const int tid = threadIdx.x;
    const int w  = tid >> 6;     // wave 0..7
    const int l  = tid & 63;
    const int lr = l & 15;       // MFMA: A-row / B-col / C-col
    const int lg = l >> 4;       // MFMA: k-group; C rows lg*4+r
    const int b0 = blockIdx.x * 16;

    const bf16x8* PW = (const bf16x8*)((const char*)WS + PACK_OFF);  // packed Wih
    const bf16x8* PH = PW + NFRAG;                                   // packed Whh

    // park Whh into LDS (one-off; 16 x 16B per thread)
    #pragma unroll
    for (int i = 0; i < 16; ++i) sWhh[tid + i*512] = PH[tid + i*512];

    const int hcol = 16*w + lr;              // hidden col owned by this lane
    const float bdh_r = ldF(&bdh[hcol]);
    const float gb_i = ldF(&bih[hcol])      + ldF(&bhh[hcol]);
    const float gb_f = ldF(&bih[NH+hcol])   + ldF(&bhh[NH+hcol]);
    const float gb_g = ldF(&bih[2*NH+hcol]) + ldF(&bhh[2*NH+hcol]);
    const float gb_o = ldF(&bih[3*NH+hcol]) + ldF(&bhh[3*NH+hcol]);

    // small weights resident in registers (proven at VGPR=128 in R2)
    bf16x8 pB0 = ldfrag(Wdh + (size_t)hcol*ND + lg*8);
    bf16x8 pB1 = ldfrag(Wdh + (size_t)hcol*ND + 32 + lg*8);
    bf16x8 qB0 = {}, qB1 = {}, qB2 = {}, qB3 = {}, rB0 = {}, rB1 = {};
    float b1_r = 0.f, b2_r = 0.f, b3_r = 0.f;
    int dcol;
    if (w < 4){
        dcol = 16*w + lr;                    // output col in D
        b1_r = ldF(&bhr[dcol]);  b2_r = ldF(&bfr[dcol]);
        qB0 = ldfrag(Whr + (size_t)dcol*NH + lg*8);
        qB1 = ldfrag(Whr + (size_t)dcol*NH + 32 + lg*8);
        qB2 = ldfrag(Whr + (size_t)dcol*NH + 64 + lg*8);
        qB3 = ldfrag(Whr + (size_t)dcol*NH + 96 + lg*8);
        rB0 = ldfrag(Wfr + (size_t)dcol*ND + lg*8);
        rB1 = ldfrag(Wfr + (size_t)dcol*ND + 32 + lg*8);
        int kb0 = lg*8;      if (dcol >= kb0 && dcol < kb0+8) rB0[dcol-kb0] = (__bf16)0.f; // zero diag
        int kb1 = 32 + lg*8; if (dcol >= kb1 && dcol < kb1+8) rB1[dcol-kb1] = (__bf16)0.f;
    } else {
        dcol = 16*(w-4) + lr;
        b3_r = ldF(&bwc[dcol]);
        qB0 = ldfrag(Wwc + (size_t)dcol*2*ND + lg*8);
        qB1 = ldfrag(Wwc + (size_t)dcol*2*ND + 32 + lg*8);
        qB2 = ldfrag(Wwc + (size_t)dcol*2*ND + 64 + lg*8);
        qB3 = ldfrag(Wwc + (size_t)dcol*2*ND + 96 + lg*8);
    }

    // elementwise mapping: 2 elems per thread; diagonal decay in registers
    const int r0 = tid >> 5;
    const int c0 = (tid & 31) * 2;
    const float wdg0 = ldF(&Wdx[(size_t)c0*ND + c0]);
    const float wdg1 = ldF(&Wdx[(size_t)(c0+1)*ND + (c0+1)]);
    const float bdx0 = ldF(&bdx[c0]);
    const float bdx1 = ldF(&bdx[c0+1]);

    float hreg[4] = {0.f,0.f,0.f,0.f};
    float creg[4] = {0.f,0.f,0.f,0.f};
    float lacc = 0.f;

    __syncthreads();   // parked weights visible

    #pragma unroll 1
    for (int t = 0; t < NT; ++t){
        const float inv_ms = WS[t];
        // ---------------- stage 0: gamma_h -> h scale; gamma_x/m/x staging ----------------
        {
            const T* drow = DL + ((size_t)(b0+lr)*NT + t)*ND;
            f32x4 acc = {0.f,0.f,0.f,0.f};
            acc = mfma16(ldfrag(drow + lg*8), pB0, acc);
            acc = mfma16(ldfrag(drow + 32 + lg*8), pB1, acc);
            #pragma unroll
            for (int r = 0; r < 4; ++r){
                float gm = __expf(-fmaxf(acc[r] + bdh_r, 0.f));
                hreg[r] *= gm;
                sAg[lg*4+r][128 + hcol] = f2bf(hreg[r]);
            }
            size_t gE = ((size_t)(b0+r0)*NT + t)*ND + c0;
            float d0, d1, m0, m1, x0, x1;
            ld2(DL + gE, d0, d1); ld2(M + gE, m0, m1); ld2(X + gE, x0, x1);
            float gx0 = __expf(-fmaxf(d0*wdg0 + bdx0, 0.f));
            float gx1 = __expf(-fmaxf(d1*wdg1 + bdx1, 0.f));
            sAal[r0][c0]      = f2bf(gx0);
            sAal[r0][c0+1]    = f2bf(gx1);
            sAal[r0][64+c0]   = f2bf(m0);
            sAal[r0][64+c0+1] = f2bf(m1);
            sAg[r0][64+c0]    = f2bf(m0);
            sAg[r0][64+c0+1]  = f2bf(m1);
            sX[r0][c0]   = x0;
            sX[r0][c0+1] = x1;
        }
        __syncthreads();
        // ---------------- stage 1: x_h (waves 0-3) | alpha (waves 4-7) ----------------
        if (w < 4){
            f32x4 acc = {0.f,0.f,0.f,0.f};
            acc = mfma16(ldbf8(&sAg[lr][128 + 0  + lg*8]), qB0, acc);
            acc = mfma16(ldbf8(&sAg[lr][128 + 32 + lg*8]), qB1, acc);
            acc = mfma16(ldbf8(&sAg[lr][128 + 64 + lg*8]), qB2, acc);
            acc = mfma16(ldbf8(&sAg[lr][128 + 96 + lg*8]), qB3, acc);
            #pragma unroll
            for (int r = 0; r < 4; ++r){
                int row = lg*4 + r;
                float xh = acc[r] + b1_r;
                sXh[row][dcol] = xh;
                float mv = bf2f(sAg[row][64+dcol]);
                float xv = sX[row][dcol];
                float xc = mv*xv + (1.f-mv)*xh;
                sXc[row][dcol] = f2bf(xc);
                lacc += fabsf(xv - xh) * mv * inv_ms;
            }
        } else {
            f32x4 acc = {0.f,0.f,0.f,0.f};
            acc = mfma16(ldbf8(&sAal[lr][0  + lg*8]), qB0, acc);
            acc = mfma16(ldbf8(&sAal[lr][32 + lg*8]), qB1, acc);
            acc = mfma16(ldbf8(&sAal[lr][64 + lg*8]), qB2, acc);
            acc = mfma16(ldbf8(&sAal[lr][96 + lg*8]), qB3, acc);
            #pragma unroll
            for (int r = 0; r < 4; ++r) sAl[lg*4+r][dcol] = acc[r] + b3_r;
        }
        __syncthreads();
        // ---------------- stage 2: z_h = x_c @ Wfr_m.T (waves 0-3) ----------------
        if (w < 4){
            f32x4 acc = {0.f,0.f,0.f,0.f};
            acc = mfma16(ldbf8(&sXc[lr][0  + lg*8]), rB0, acc);
            acc = mfma16(ldbf8(&sXc[lr][32 + lg*8]), rB1, acc);
            #pragma unroll
            for (int r = 0; r < 4; ++r) sZh[lg*4+r][dcol] = acc[r] + b2_r;
        }
        __syncthreads();
        // ---------------- stage 3: combine, losses, c_c, output ----------------
        {
            size_t g = ((size_t)(b0+r0)*NT + t)*ND + c0;
            #pragma unroll
            for (int e = 0; e < 2; ++e){
                int col = c0 + e;
                float xv = sX[r0][col];
                float mv = bf2f(sAg[r0][64+col]);
                float zh = sZh[r0][col];
                float xh = sXh[r0][col];
                float al = sAl[r0][col];
                float ch = al*zh + (1.f-al)*xh;
                lacc += (fabsf(xv - zh) + fabsf(xv - ch)) * mv * inv_ms;
                float cc = mv*xv + (1.f-mv)*ch;
                stF(&OUT[1 + g + e], cc);
                sAg[r0][col] = f2bf(cc);
            }
        }
        __syncthreads();
        // ---------------- stage 4: gates + LSTM update ----------------
        {
            bf16x8 af[8];
            #pragma unroll
            for (int kk = 0; kk < 8; ++kk) af[kk] = ldbf8(&sAg[lr][kk*32 + lg*8]);
            const int wb = w*64 + l;
            f32x4 gacc[4];
            #pragma unroll
            for (int g = 0; g < 4; ++g){
                // Wih-part (packed bf16, L2): frag fi = g*2048 + kk*512 + wb
                const bf16x8* pw = PW + g*2048 + wb;
                bf16x8 w0 = pw[0], w1 = pw[512], w2 = pw[1024], w3 = pw[1536];
                // Whh-part (parked in LDS)
                const bf16x8* ph = sWhh + g*2048 + wb;
                bf16x8 h0 = ph[0], h1 = ph[512], h2 = ph[1024], h3 = ph[1536];
                f32x4 a = {0.f,0.f,0.f,0.f};
                a = mfma16(af[0], w0, a);
                a = mfma16(af[1], w1, a);
                a = mfma16(af[2], w2, a);
                a = mfma16(af[3], w3, a);
                a = mfma16(af[4], h0, a);
                a = mfma16(af[5], h1, a);
                a = mfma16(af[6], h2, a);
                a = mfma16(af[7], h3, a);
                gacc[g] = a;
            }
            #pragma unroll
            for (int r = 0; r < 4; ++r){
                float iv = fsig(gacc[0][r] + gb_i);
                float fv = fsig(gacc[1][r] + gb_f);
                float gv = ftanh(gacc[2][r] + gb_g);
                float ov = fsig(gacc[3][r] + gb_o);
                creg[r] = fv*creg[r] + iv*gv;
                hreg[r] = ov*ftanh(creg[r]);
            }
        }
        __syncthreads();
    }

    // loss reduction: per-wave shuffle, block partial -> ws (deterministic final sum)
    #pragma unroll
    for (int off = 32; off > 0; off >>= 1) lacc += __shfl_down(lacc, off);
    if (l == 0) sRed[w] = lacc;
    __syncthreads();
    if (tid == 0){
        float s = 0.f;
        #pragma unroll
        for (int i = 0; i < 8; ++i) s += sRed[i];
        WS[PART_IDX + blockIdx.x] = s;
    }
}

// --------------------- finalize: deterministic loss sum ---------------------
template<typename T>
__global__ void fin_kernel(const float* __restrict__ WS, T* __restrict__ OUT){
    if (WS[FLAG_IDX] != wantFlag<T>()) return;
    if (threadIdx.x == 0 && blockIdx.x == 0){
        float s = 0.f;
        for (int i = 0; i < 32; ++i) s += WS[PART_IDX + i];
        stF(&OUT[0], s / (float)NT);
    }
}

template<typename T>
static void launch_all(void* const* d_in, void* d_out, float* WS, hipStream_t stream){
    const T* X   = (const T*)d_in[0];
    const T* M   = (const T*)d_in[1];
    const T* DL  = (const T*)d_in[2];
    const T* Wdh = (const T*)d_in[3];
    const T* bdh = (const T*)d_in[4];
    const T* Wdx = (const T*)d_in[5];
    const T* bdx = (const T*)d_in[6];
    const T* Whr = (const T*)d_in[7];
    const T* bhr = (const T*)d_in[8];
    const T* Wfr = (const T*)d_in[9];
    const T* bfr = (const T*)d_in[10];
    const T* Wwc = (const T*)d_in[11];
    const T* bwc = (const T*)d_in[12];
    const T* Wih = (const T*)d_in[13];
    const T* Whh = (const T*)d_in[14];
    const T* bih = (const T*)d_in[15];
    const T* bhh = (const T*)d_in[16];
    T* OUT = (T*)d_out;

    static bool attr_done_f32 = false, attr_done_bf16 = false;
    bool& attr_done = (sizeof(T) == 4) ? attr_done_f32 : attr_done_bf16;
    if (!attr_done){
        (void)hipFuncSetAttribute((const void*)brits_main<T>,
                                  hipFuncAttributeMaxDynamicSharedMemorySize, 131072);
        attr_done = true;
    }

    pack_kernel<T><<<dim3(32), dim3(256), 0, stream>>>(Wih, Whh, WS);
    msum_kernel<T><<<dim3(NT), dim3(256), 0, stream>>>(M, WS);
    brits_main<T><<<dim3(32), dim3(512), 131072, stream>>>(X, M, DL, Wdh, bdh, Wdx, bdx,
                                                           Whr, bhr, Wfr, bfr, Wwc, bwc,
                                                           Wih, Whh, bih, bhh, OUT, WS);
    fin_kernel<T><<<dim3(1), dim3(64), 0, stream>>>(WS, OUT);
}

extern "C" void kernel_launch(void* const* d_in, const int* in_sizes, int n_in,
                              void* d_out, int out_size, void* d_ws, size_t ws_size,
                              hipStream_t stream) {
    float* WS = (float*)d_ws;
    detect_kernel<<<dim3(1), dim3(64), 0, stream>>>(d_in[0], WS);
    launch_all<__hip_bfloat16>(d_in, d_out, WS, stream);
    launch_all<float>(d_in, d_out, WS, stream);
}

// Round 7
// 805.163 us; speedup vs baseline: 1.4888x; 1.4888x over previous
//
#include <hip/hip_runtime.h>
#include <hip/hip_bf16.h>

typedef __bf16 bf16x8 __attribute__((ext_vector_type(8)));
typedef float f32x4 __attribute__((ext_vector_type(4)));

#define NB 512
#define NT 256
#define ND 64
#define NH 128
#define PART_IDX 256   /* WS float slots 256..287: per-block loss partials */
#define FLAG_IDX 320   /* WS float slot: 1.0 = inputs are f32, 0.0 = bf16 */

__device__ __forceinline__ float bf2f(__hip_bfloat16 v){ return __bfloat162float(v); }
__device__ __forceinline__ __hip_bfloat16 f2bf(float v){ return __float2bfloat16(v); }

__device__ __forceinline__ float ldF(const float* p){ return *p; }
__device__ __forceinline__ float ldF(const __hip_bfloat16* p){ return __bfloat162float(*p); }
__device__ __forceinline__ void  stF(float* p, float v){ *p = v; }
__device__ __forceinline__ void  stF(__hip_bfloat16* p, float v){ *p = __float2bfloat16(v); }

// paired load -> 2 floats
__device__ __forceinline__ void ld2(const float* p, float& a, float& b){
    float2 v = *reinterpret_cast<const float2*>(p); a = v.x; b = v.y;
}
__device__ __forceinline__ void ld2(const __hip_bfloat16* p, float& a, float& b){
    unsigned u = *reinterpret_cast<const unsigned*>(p);
    unsigned short s0 = (unsigned short)(u & 0xffffu), s1 = (unsigned short)(u >> 16);
    a = __bfloat162float(*reinterpret_cast<__hip_bfloat16*>(&s0));
    b = __bfloat162float(*reinterpret_cast<__hip_bfloat16*>(&s1));
}

// dtype-generic 8-element MFMA fragment load (16B for bf16, 32B for f32 + cvt)
__device__ __forceinline__ bf16x8 ldfrag(const __hip_bfloat16* p){
    return *reinterpret_cast<const bf16x8*>(p);
}
__device__ __forceinline__ bf16x8 ldfrag(const float* p){
    f32x4 a = *reinterpret_cast<const f32x4*>(p);
    f32x4 b = *reinterpret_cast<const f32x4*>(p + 4);
    bf16x8 r;
    #pragma unroll
    for (int i = 0; i < 4; ++i){
        __hip_bfloat16 ha = __float2bfloat16(a[i]);
        __hip_bfloat16 hb = __float2bfloat16(b[i]);
        r[i]   = *reinterpret_cast<__bf16*>(&ha);
        r[4+i] = *reinterpret_cast<__bf16*>(&hb);
    }
    return r;
}
__device__ __forceinline__ bf16x8 ldbf8(const __hip_bfloat16* p){
    return *reinterpret_cast<const bf16x8*>(p);
}

template<typename T> __device__ __forceinline__ float wantFlag(){ return sizeof(T)==4 ? 1.f : 0.f; }

__device__ __forceinline__ f32x4 mfma16(bf16x8 a, bf16x8 b, f32x4 c){
    return __builtin_amdgcn_mfma_f32_16x16x32_bf16(a, b, c, 0, 0, 0);
}
__device__ __forceinline__ float fsig(float x){ return 1.f/(1.f+__expf(-x)); }
__device__ __forceinline__ float ftanh(float x){ return 1.f - 2.f/(__expf(2.f*x)+1.f); }

// --------------------- kernel 0: input dtype detection ---------------------
__global__ void detect_kernel(const void* __restrict__ x, float* __restrict__ WS){
    if (threadIdx.x == 0 && blockIdx.x == 0){
        const unsigned short* u = (const unsigned short*)x;
        int weird = 0;
        for (int i = 0; i < 256; ++i){
            unsigned e = (u[i] >> 7) & 0xFF;
            if (e == 0xFF || e >= 0x8A || (e != 0 && e <= 0x5A)) ++weird;
        }
        WS[FLAG_IDX] = (weird >= 16) ? 1.f : 0.f;
    }
}

// --------------------- kernel 1: per-step inverse mask sum ---------------------
template<typename T>
__global__ __launch_bounds__(256) void msum_kernel(const T* __restrict__ M,
                                                   float* __restrict__ WS){
    if (WS[FLAG_IDX] != wantFlag<T>()) return;
    int t = blockIdx.x;
    int tid = threadIdx.x;
    int col = tid & 63;
    int bg  = tid >> 6;
    float s = 0.f;
    for (int b = bg; b < NB; b += 4)
        s += ldF(&M[((size_t)b*NT + t)*ND + col]);
    #pragma unroll
    for (int off = 32; off > 0; off >>= 1) s += __shfl_down(s, off);
    __shared__ float r4[4];
    if ((tid & 63) == 0) r4[bg] = s;
    __syncthreads();
    if (tid == 0) WS[t] = 1.f / (r4[0] + r4[1] + r4[2] + r4[3] + 1e-5f);
}

// --------------------- main: 32 blocks x 512 threads, 16 batch rows each ---------------------
template<typename T>
__global__ __launch_bounds__(512, 2) void brits_main(
    const T* __restrict__ X,  const T* __restrict__ M,
    const T* __restrict__ DL,
    const T* __restrict__ Wdh, const T* __restrict__ bdh,
    const T* __restrict__ Wdx, const T* __restrict__ bdx,
    const T* __restrict__ Whr, const T* __restrict__ bhr,
    const T* __restrict__ Wfr, const T* __restrict__ bfr,
    const T* __restrict__ Wwc, const T* __restrict__ bwc,
    const T* __restrict__ Wih, const T* __restrict__ Whh,
    const T* __restrict__ bih, const T* __restrict__ bhh,
    T* __restrict__ OUT, float* __restrict__ WS)
{
    if (WS[FLAG_IDX] != wantFlag<T>()) return;

    // LDS (rows padded to de-conflict ds_read_b128 fragment loads)
    __shared__ __align__(16) __hip_bfloat16 sAg[16][264];   // [ c_c(0:64) | m(64:128) | h_bf(128:256) ]
    __shared__ __align__(16) __hip_bfloat16 sAal[16][136];  // [ gamma_x(0:64) | m(64:128) ]
    __shared__ __align__(16) __hip_bfloat16 sXc[16][72];    // x_c
    __shared__ __align__(16) __hip_bfloat16 sDL[16][72];    // d(t) bf16 (A-frags for gamma_h)
    __shared__ float sX [16][68];                           // x(t) as f32 (exact for both dtypes)
    __shared__ float sXh[16][68];
    __shared__ float sZh[16][68];
    __shared__ float sAl[16][68];
    __shared__ float sRed[8];

    const int tid = threadIdx.x;
    const int w  = tid >> 6;     // wave 0..7
    const int l  = tid & 63;
    const int lr = l & 15;       // MFMA: A-row / B-col / C-col
    const int lg = l >> 4;       // MFMA: k-group; C rows lg*4+r
    const int b0 = blockIdx.x * 16;

    const int hcol = 16*w + lr;              // hidden col owned by this lane
    const float bdh_r = ldF(&bdh[hcol]);
    const float gb_i = ldF(&bih[hcol])      + ldF(&bhh[hcol]);
    const float gb_f = ldF(&bih[NH+hcol])   + ldF(&bhh[NH+hcol]);
    const float gb_g = ldF(&bih[2*NH+hcol]) + ldF(&bhh[2*NH+hcol]);
    const float gb_o = ldF(&bih[3*NH+hcol]) + ldF(&bhh[3*NH+hcol]);

    // small-weight B fragments resident (constant over t) -- proven at VGPR=128 in R2
    bf16x8 pB0 = ldfrag(Wdh + (size_t)hcol*ND + lg*8);
    bf16x8 pB1 = ldfrag(Wdh + (size_t)hcol*ND + 32 + lg*8);
    bf16x8 qB0 = {}, qB1 = {}, qB2 = {}, qB3 = {}, rB0 = {}, rB1 = {};
    float b1_r = 0.f, b2_r = 0.f, b3_r = 0.f;
    int dcol;
    if (w < 4){
        dcol = 16*w + lr;                    // output col in D
        b1_r = ldF(&bhr[dcol]);  b2_r = ldF(&bfr[dcol]);
        qB0 = ldfrag(Whr + (size_t)dcol*NH + lg*8);
        qB1 = ldfrag(Whr + (size_t)dcol*NH + 32 + lg*8);
        qB2 = ldfrag(Whr + (size_t)dcol*NH + 64 + lg*8);
        qB3 = ldfrag(Whr + (size_t)dcol*NH + 96 + lg*8);
        rB0 = ldfrag(Wfr + (size_t)dcol*ND + lg*8);
        rB1 = ldfrag(Wfr + (size_t)dcol*ND + 32 + lg*8);
        int kb0 = lg*8;      if (dcol >= kb0 && dcol < kb0+8) rB0[dcol-kb0] = (__bf16)0.f; // zero diag
        int kb1 = 32 + lg*8; if (dcol >= kb1 && dcol < kb1+8) rB1[dcol-kb1] = (__bf16)0.f;
    } else {
        dcol = 16*(w-4) + lr;
        b3_r = ldF(&bwc[dcol]);
        qB0 = ldfrag(Wwc + (size_t)dcol*2*ND + lg*8);
        qB1 = ldfrag(Wwc + (size_t)dcol*2*ND + 32 + lg*8);
        qB2 = ldfrag(Wwc + (size_t)dcol*2*ND + 64 + lg*8);
        qB3 = ldfrag(Wwc + (size_t)dcol*2*ND + 96 + lg*8);
    }

    // elementwise mapping: 2 elems per thread; diagonal decay in registers
    const int r0 = tid >> 5;
    const int c0 = (tid & 31) * 2;
    const float wdg0 = ldF(&Wdx[(size_t)c0*ND + c0]);
    const float wdg1 = ldF(&Wdx[(size_t)(c0+1)*ND + (c0+1)]);
    const float bdx0 = ldF(&bdx[c0]);
    const float bdx1 = ldF(&bdx[c0+1]);

    float hreg[4] = {0.f,0.f,0.f,0.f};
    float creg[4] = {0.f,0.f,0.f,0.f};
    float lacc = 0.f;

    // prefetch registers (t-step inputs, loaded one stage ahead)
    float pd0, pd1, pm0, pm1, px0, px1;

    // ---- prologue: load t=0 inputs, stage sDL, zero h ----
    {
        size_t g0 = ((size_t)(b0+r0)*NT + 0)*ND + c0;
        ld2(DL + g0, pd0, pd1);
        ld2(M  + g0, pm0, pm1);
        ld2(X  + g0, px0, px1);
        sDL[r0][c0]   = f2bf(pd0);
        sDL[r0][c0+1] = f2bf(pd1);
        #pragma unroll
        for (int r = 0; r < 4; ++r) sAg[lg*4+r][128 + hcol] = f2bf(0.f);
    }
    float inv_cur = WS[0];
    __syncthreads();

    #pragma unroll 1
    for (int t = 0; t < NT; ++t){
        const float inv_ms = inv_cur;
        // ---------------- stage 0: gamma_h (from sDL) + elementwise staging (from regs) ----------------
        {
            f32x4 acc = {0.f,0.f,0.f,0.f};
            acc = mfma16(ldbf8(&sDL[lr][0  + lg*8]), pB0, acc);
            acc = mfma16(ldbf8(&sDL[lr][32 + lg*8]), pB1, acc);
            #pragma unroll
            for (int r = 0; r < 4; ++r){
                float gm = __expf(-fmaxf(acc[r] + bdh_r, 0.f));
                hreg[r] *= gm;
                sAg[lg*4+r][128 + hcol] = f2bf(hreg[r]);
            }
            float gx0 = __expf(-fmaxf(pd0*wdg0 + bdx0, 0.f));
            float gx1 = __expf(-fmaxf(pd1*wdg1 + bdx1, 0.f));
            sAal[r0][c0]      = f2bf(gx0);
            sAal[r0][c0+1]    = f2bf(gx1);
            sAal[r0][64+c0]   = f2bf(pm0);
            sAal[r0][64+c0+1] = f2bf(pm1);
            sAg[r0][64+c0]    = f2bf(pm0);
            sAg[r0][64+c0+1]  = f2bf(pm1);
            sX[r0][c0]   = px0;
            sX[r0][c0+1] = px1;
        }
        __syncthreads();
        // ---------------- stage 1: x_h (waves 0-3) | alpha (waves 4-7) ----------------
        if (w < 4){
            f32x4 acc = {0.f,0.f,0.f,0.f};
            acc = mfma16(ldbf8(&sAg[lr][128 + 0  + lg*8]), qB0, acc);
            acc = mfma16(ldbf8(&sAg[lr][128 + 32 + lg*8]), qB1, acc);
            acc = mfma16(ldbf8(&sAg[lr][128 + 64 + lg*8]), qB2, acc);
            acc = mfma16(ldbf8(&sAg[lr][128 + 96 + lg*8]), qB3, acc);
            #pragma unroll
            for (int r = 0; r < 4; ++r){
                int row = lg*4 + r;
                float xh = acc[r] + b1_r;
                sXh[row][dcol] = xh;
                float mv = bf2f(sAg[row][64+dcol]);
                float xv = sX[row][dcol];
                float xc = mv*xv + (1.f-mv)*xh;
                sXc[row][dcol] = f2bf(xc);
                lacc += fabsf(xv - xh) * mv * inv_ms;
            }
        } else {
            f32x4 acc = {0.f,0.f,0.f,0.f};
            acc = mfma16(ldbf8(&sAal[lr][0  + lg*8]), qB0, acc);
            acc = mfma16(ldbf8(&sAal[lr][32 + lg*8]), qB1, acc);
            acc = mfma16(ldbf8(&sAal[lr][64 + lg*8]), qB2, acc);
            acc = mfma16(ldbf8(&sAal[lr][96 + lg*8]), qB3, acc);
            #pragma unroll
            for (int r = 0; r < 4; ++r) sAl[lg*4+r][dcol] = acc[r] + b3_r;
        }
        __syncthreads();
        // ---------------- stage 2: z_h = x_c @ Wfr_m.T (waves 0-3) ----------------
        if (w < 4){
            f32x4 acc = {0.f,0.f,0.f,0.f};
            acc = mfma16(ldbf8(&sXc[lr][0  + lg*8]), rB0, acc);
            acc = mfma16(ldbf8(&sXc[lr][32 + lg*8]), rB1, acc);
            #pragma unroll
            for (int r = 0; r < 4; ++r) sZh[lg*4+r][dcol] = acc[r] + b2_r;
        }
        __syncthreads();
        // ---------------- stage 3: combine, losses, c_c, output ----------------
        {
            size_t g = ((size_t)(b0+r0)*NT + t)*ND + c0;
            #pragma unroll
            for (int e = 0; e < 2; ++e){
                int col = c0 + e;
                float xv = sX[r0][col];
                float mv = bf2f(sAg[r0][64+col]);
                float zh = sZh[r0][col];
                float xh = sXh[r0][col];
                float al = sAl[r0][col];
                float ch = al*zh + (1.f-al)*xh;
                lacc += (fabsf(xv - zh) + fabsf(xv - ch)) * mv * inv_ms;
                float cc = mv*xv + (1.f-mv)*ch;
                stF(&OUT[1 + g + e], cc);
                sAg[r0][col] = f2bf(cc);
            }
        }
        __syncthreads();
        // ---------------- stage 4: prefetch t+1, gates + LSTM update, stage sDL ----------------
        {
            // issue t+1 input loads FIRST; gates compute below covers their latency,
            // and the stage-4-end __syncthreads (vmcnt drain) completes them for free.
            const int tn = (t+1 < NT) ? t+1 : t;
            size_t gE = ((size_t)(b0+r0)*NT + tn)*ND + c0;
            ld2(DL + gE, pd0, pd1);
            ld2(M  + gE, pm0, pm1);
            ld2(X  + gE, px0, px1);
            float inv_next = WS[tn];

            bf16x8 af[8];
            #pragma unroll
            for (int kk = 0; kk < 8; ++kk) af[kk] = ldbf8(&sAg[lr][kk*32 + lg*8]);
            const T* wih_b = Wih + (size_t)hcol*128;
            const T* whh_b = Whh + (size_t)hcol*128;
            f32x4 gacc[4];
            #pragma unroll
            for (int g = 0; g < 4; ++g){
                const T* wr = wih_b + (size_t)g*NH*128;
                const T* hr = whh_b + (size_t)g*NH*128;
                f32x4 a = {0.f,0.f,0.f,0.f};
                a = mfma16(af[0], ldfrag(wr + 0  + lg*8), a);
                a = mfma16(af[1], ldfrag(wr + 32 + lg*8), a);
                a = mfma16(af[2], ldfrag(wr + 64 + lg*8), a);
                a = mfma16(af[3], ldfrag(wr + 96 + lg*8), a);
                a = mfma16(af[4], ldfrag(hr + 0  + lg*8), a);
                a = mfma16(af[5], ldfrag(hr + 32 + lg*8), a);
                a = mfma16(af[6], ldfrag(hr + 64 + lg*8), a);
                a = mfma16(af[7], ldfrag(hr + 96 + lg*8), a);
                gacc[g] = a;
            }
            #pragma unroll
            for (int r = 0; r < 4; ++r){
                float iv = fsig(gacc[0][r] + gb_i);
                float fv = fsig(gacc[1][r] + gb_f);
                float gv = ftanh(gacc[2][r] + gb_g);
                float ov = fsig(gacc[3][r] + gb_o);
                creg[r] = fv*creg[r] + iv*gv;
                hreg[r] = ov*ftanh(creg[r]);
            }
            // stage d(t+1) into LDS for next step's gamma_h A-frags
            sDL[r0][c0]   = f2bf(pd0);
            sDL[r0][c0+1] = f2bf(pd1);
            inv_cur = inv_next;
        }
        __syncthreads();
    }

    // loss reduction: per-wave shuffle, block partial -> ws (deterministic final sum)
    #pragma unroll
    for (int off = 32; off > 0; off >>= 1) lacc += __shfl_down(lacc, off);
    if (l == 0) sRed[w] = lacc;
    __syncthreads();
    if (tid == 0){
        float s = 0.f;
        #pragma unroll
        for (int i = 0; i < 8; ++i) s += sRed[i];
        WS[PART_IDX + blockIdx.x] = s;
    }
}

// --------------------- finalize: deterministic loss sum ---------------------
template<typename T>
__global__ void fin_kernel(const float* __restrict__ WS, T* __restrict__ OUT){
    if (WS[FLAG_IDX] != wantFlag<T>()) return;
    if (threadIdx.x == 0 && blockIdx.x == 0){
        float s = 0.f;
        for (int i = 0; i < 32; ++i) s += WS[PART_IDX + i];
        stF(&OUT[0], s / (float)NT);
    }
}

template<typename T>
static void launch_all(void* const* d_in, void* d_out, float* WS, hipStream_t stream){
    const T* X   = (const T*)d_in[0];
    const T* M   = (const T*)d_in[1];
    const T* DL  = (const T*)d_in[2];
    const T* Wdh = (const T*)d_in[3];
    const T* bdh = (const T*)d_in[4];
    const T* Wdx = (const T*)d_in[5];
    const T* bdx = (const T*)d_in[6];
    const T* Whr = (const T*)d_in[7];
    const T* bhr = (const T*)d_in[8];
    const T* Wfr = (const T*)d_in[9];
    const T* bfr = (const T*)d_in[10];
    const T* Wwc = (const T*)d_in[11];
    const T* bwc = (const T*)d_in[12];
    const T* Wih = (const T*)d_in[13];
    const T* Whh = (const T*)d_in[14];
    const T* bih = (const T*)d_in[15];
    const T* bhh = (const T*)d_in[16];
    T* OUT = (T*)d_out;
    msum_kernel<T><<<dim3(NT), dim3(256), 0, stream>>>(M, WS);
    brits_main<T><<<dim3(32), dim3(512), 0, stream>>>(X, M, DL, Wdh, bdh, Wdx, bdx,
                                                      Whr, bhr, Wfr, bfr, Wwc, bwc,
                                                      Wih, Whh, bih, bhh, OUT, WS);
    fin_kernel<T><<<dim3(1), dim3(64), 0, stream>>>(WS, OUT);
}

extern "C" void kernel_launch(void* const* d_in, const int* in_sizes, int n_in,
                              void* d_out, int out_size, void* d_ws, size_t ws_size,
                              hipStream_t stream) {
    float* WS = (float*)d_ws;
    detect_kernel<<<dim3(1), dim3(64), 0, stream>>>(d_in[0], WS);
    launch_all<__hip_bfloat16>(d_in, d_out, WS, stream);
    launch_all<float>(d_in, d_out, WS, stream);
}